// Round 1
// baseline (9991.845 us; speedup 1.0000x reference)
//
#include <hip/hip_runtime.h>
#include <hip/hip_bf16.h>
#include <math.h>

// Problem constants (from reference): N=131072 tokens, D=512, DFF=1024,
// 8 heads x head_dim 64, attention blocks of 256 tokens -> 512 blocks.
#define NTOK 131072
#define DMODEL 512
#define DFF_ 1024
#define NHEAD 8
#define HD 64
#define BLK 256
#define NB (NTOK / BLK)

typedef __hip_bfloat16 bf16;

__device__ __forceinline__ float bf_to_f(unsigned short u) {
    return __uint_as_float(((unsigned)u) << 16);
}
__device__ __forceinline__ unsigned short f_to_bf(float f) {
    bf16 h = __float2bfloat16(f);  // RNE
    return __builtin_bit_cast(unsigned short, h);
}

// ---- 4-element loads (A operand may be fp32 or bf16) ----
__device__ __forceinline__ void loadA4(const float* p, float& a0, float& a1, float& a2, float& a3) {
    float4 v = *(const float4*)p;
    a0 = v.x; a1 = v.y; a2 = v.z; a3 = v.w;
}
__device__ __forceinline__ void loadA4(const bf16* p, float& a0, float& a1, float& a2, float& a3) {
    ushort4 v = *(const ushort4*)p;
    a0 = bf_to_f(v.x); a1 = bf_to_f(v.y); a2 = bf_to_f(v.z); a3 = bf_to_f(v.w);
}
// ---- 4-element stores (C may be fp32 or bf16) ----
__device__ __forceinline__ void store4(float* p, float a, float b, float c, float d) {
    float4 v; v.x = a; v.y = b; v.z = c; v.w = d;
    *(float4*)p = v;
}
__device__ __forceinline__ void store4(bf16* p, float a, float b, float c, float d) {
    ushort4 v; v.x = f_to_bf(a); v.y = f_to_bf(b); v.z = f_to_bf(c); v.w = f_to_bf(d);
    *(ushort4*)p = v;
}

// =====================================================================
// Tiled fp32 GEMM:  C[M,Nn] = A[M,K] * B[Nn,K]^T + bias (+resid) (gelu?)
// Both A and B are row-major over K ("NT" layout) -- matches all four
// matmuls in this layer since weights are [out_features, in_features].
// BM=BN=64, BK=16, 256 threads, 4x4 micro-tile per thread.
// =====================================================================
template <typename TA, typename TO, bool RESID, bool DO_GELU>
__global__ __launch_bounds__(256) void gemm_nt(const TA* __restrict__ A,
                                               const float* __restrict__ B,
                                               const float* __restrict__ bias,
                                               const float* __restrict__ resid,
                                               TO* __restrict__ C,
                                               int M, int Nn, int K) {
    __shared__ float As[16][68];  // [k][m], padded to break bank conflicts
    __shared__ float Bs[16][68];  // [k][n]

    const int tid = threadIdx.x;
    const int m0 = blockIdx.y << 6;
    const int n0 = blockIdx.x << 6;
    const int lrow = tid >> 2;         // 0..63 : tile row for loads
    const int lcg  = (tid & 3) << 2;   // 0,4,8,12 : k-offset for loads
    const int tm = tid >> 4;           // 0..15
    const int tn = tid & 15;           // 0..15

    float acc[4][4] = {{0.f, 0.f, 0.f, 0.f}, {0.f, 0.f, 0.f, 0.f},
                       {0.f, 0.f, 0.f, 0.f}, {0.f, 0.f, 0.f, 0.f}};

    for (int k0 = 0; k0 < K; k0 += 16) {
        float a0, a1, a2, a3;
        loadA4(A + (size_t)(m0 + lrow) * K + (k0 + lcg), a0, a1, a2, a3);
        float4 bv = *(const float4*)(B + (size_t)(n0 + lrow) * K + (k0 + lcg));
        As[lcg + 0][lrow] = a0; As[lcg + 1][lrow] = a1;
        As[lcg + 2][lrow] = a2; As[lcg + 3][lrow] = a3;
        Bs[lcg + 0][lrow] = bv.x; Bs[lcg + 1][lrow] = bv.y;
        Bs[lcg + 2][lrow] = bv.z; Bs[lcg + 3][lrow] = bv.w;
        __syncthreads();
#pragma unroll
        for (int kk = 0; kk < 16; ++kk) {
            float4 av = *(const float4*)&As[kk][tm << 2];
            float4 bb = *(const float4*)&Bs[kk][tn << 2];
            float am[4] = {av.x, av.y, av.z, av.w};
            float bn[4] = {bb.x, bb.y, bb.z, bb.w};
#pragma unroll
            for (int i = 0; i < 4; ++i)
#pragma unroll
                for (int j = 0; j < 4; ++j)
                    acc[i][j] = fmaf(am[i], bn[j], acc[i][j]);
        }
        __syncthreads();
    }

    const int nc = n0 + (tn << 2);
    float4 bsv = *(const float4*)(bias + nc);
#pragma unroll
    for (int i = 0; i < 4; ++i) {
        const int m = m0 + (tm << 2) + i;
        float v0 = acc[i][0] + bsv.x;
        float v1 = acc[i][1] + bsv.y;
        float v2 = acc[i][2] + bsv.z;
        float v3 = acc[i][3] + bsv.w;
        if constexpr (RESID) {
            float4 r = *(const float4*)(resid + (size_t)m * Nn + nc);
            v0 += r.x; v1 += r.y; v2 += r.z; v3 += r.w;
        }
        if constexpr (DO_GELU) {
            v0 = 0.5f * v0 * (1.f + erff(v0 * 0.70710678118654752f));
            v1 = 0.5f * v1 * (1.f + erff(v1 * 0.70710678118654752f));
            v2 = 0.5f * v2 * (1.f + erff(v2 * 0.70710678118654752f));
            v3 = 0.5f * v3 * (1.f + erff(v3 * 0.70710678118654752f));
        }
        store4(C + (size_t)m * Nn + nc, v0, v1, v2, v3);
    }
}

// =====================================================================
// Per-(block, head) attention. qkv is [N,1536] bf16 (q|k|v each 512).
// One workgroup = one (block b, head h): K,V rows staged in LDS fp32,
// thread t = query token t, online-softmax flash loop over 256 keys.
// ctx written fp32 to d_out (used as scratch) in [N, 512] head-major.
// =====================================================================
__global__ __launch_bounds__(256) void attn_kernel(const bf16* __restrict__ qkv,
                                                   float* __restrict__ ctx) {
    __shared__ float Ks[BLK][68];  // 69,632 B
    __shared__ float Vs[BLK][68];  // total 139,264 B < 160 KiB
    const int b = blockIdx.x >> 3;
    const int h = blockIdx.x & 7;
    const int t = threadIdx.x;

    const bf16* qrow = qkv + (size_t)(b * BLK + t) * 1536 + h * HD;
    const bf16* krow = qrow + DMODEL;
    const bf16* vrow = qrow + 2 * DMODEL;

    float q[HD];
#pragma unroll
    for (int j = 0; j < HD; j += 4) {
        ushort4 kv = *(const ushort4*)(krow + j);
        Ks[t][j + 0] = bf_to_f(kv.x); Ks[t][j + 1] = bf_to_f(kv.y);
        Ks[t][j + 2] = bf_to_f(kv.z); Ks[t][j + 3] = bf_to_f(kv.w);
        ushort4 vv = *(const ushort4*)(vrow + j);
        Vs[t][j + 0] = bf_to_f(vv.x); Vs[t][j + 1] = bf_to_f(vv.y);
        Vs[t][j + 2] = bf_to_f(vv.z); Vs[t][j + 3] = bf_to_f(vv.w);
        ushort4 qv = *(const ushort4*)(qrow + j);
        q[j + 0] = bf_to_f(qv.x) * 0.125f;  // fold 1/sqrt(64) into q
        q[j + 1] = bf_to_f(qv.y) * 0.125f;
        q[j + 2] = bf_to_f(qv.z) * 0.125f;
        q[j + 3] = bf_to_f(qv.w) * 0.125f;
    }
    __syncthreads();

    float m = -1e30f, l = 0.f;
    float acc[HD];
#pragma unroll
    for (int j = 0; j < HD; ++j) acc[j] = 0.f;

    for (int s = 0; s < BLK; ++s) {
        // 4 partial sums to break the fma dependence chain
        float e0 = 0.f, e1 = 0.f, e2 = 0.f, e3 = 0.f;
#pragma unroll
        for (int j = 0; j < HD; j += 4) {
            e0 = fmaf(q[j + 0], Ks[s][j + 0], e0);
            e1 = fmaf(q[j + 1], Ks[s][j + 1], e1);
            e2 = fmaf(q[j + 2], Ks[s][j + 2], e2);
            e3 = fmaf(q[j + 3], Ks[s][j + 3], e3);
        }
        float e = (e0 + e1) + (e2 + e3);
        float mn = fmaxf(m, e);
        float corr = __expf(m - mn);
        float p = __expf(e - mn);
        l = l * corr + p;
#pragma unroll
        for (int j = 0; j < HD; ++j)
            acc[j] = fmaf(acc[j], corr, p * Vs[s][j]);
        m = mn;
    }

    const float inv = 1.f / l;
    float* orow = ctx + (size_t)(b * BLK + t) * DMODEL + h * HD;
#pragma unroll
    for (int j = 0; j < HD; j += 4) {
        float4 o;
        o.x = acc[j + 0] * inv; o.y = acc[j + 1] * inv;
        o.z = acc[j + 2] * inv; o.w = acc[j + 3] * inv;
        *(float4*)(orow + j) = o;
    }
}

// =====================================================================
// Row LayerNorm over 512 cols. One wave per row (4 rows / 256-block).
// Safe in-place (each row read+written by the same wave).
// =====================================================================
__global__ __launch_bounds__(256) void ln_rows(const float* __restrict__ in,
                                               float* __restrict__ out,
                                               const float* __restrict__ gg,
                                               const float* __restrict__ bb) {
    const int lane = threadIdx.x & 63;
    const int wv = threadIdx.x >> 6;
    const size_t row = (size_t)blockIdx.x * 4 + wv;
    const float* p = in + row * DMODEL + lane * 8;
    float4 a = ((const float4*)p)[0];
    float4 c = ((const float4*)p)[1];
    float s  = a.x + a.y + a.z + a.w + c.x + c.y + c.z + c.w;
    float ss = a.x * a.x + a.y * a.y + a.z * a.z + a.w * a.w +
               c.x * c.x + c.y * c.y + c.z * c.z + c.w * c.w;
#pragma unroll
    for (int off = 1; off < 64; off <<= 1) {
        s  += __shfl_xor(s, off, 64);
        ss += __shfl_xor(ss, off, 64);
    }
    const float mu = s * (1.f / 512.f);
    const float var = ss * (1.f / 512.f) - mu * mu;
    const float rstd = 1.f / sqrtf(var + 1e-5f);
    const int c0 = lane * 8;
    float4 g0 = *(const float4*)(gg + c0), g1 = *(const float4*)(gg + c0 + 4);
    float4 b0 = *(const float4*)(bb + c0), b1 = *(const float4*)(bb + c0 + 4);
    float4 o0, o1;
    o0.x = (a.x - mu) * rstd * g0.x + b0.x;
    o0.y = (a.y - mu) * rstd * g0.y + b0.y;
    o0.z = (a.z - mu) * rstd * g0.z + b0.z;
    o0.w = (a.w - mu) * rstd * g0.w + b0.w;
    o1.x = (c.x - mu) * rstd * g1.x + b1.x;
    o1.y = (c.y - mu) * rstd * g1.y + b1.y;
    o1.z = (c.z - mu) * rstd * g1.z + b1.z;
    o1.w = (c.w - mu) * rstd * g1.w + b1.w;
    float* qp = out + row * DMODEL + c0;
    ((float4*)qp)[0] = o0;
    ((float4*)qp)[1] = o1;
}

// =====================================================================
// Workspace layout (needs ws_size >= 512 MiB):
//   ws_qkv bf16 [N,1536] @ 0        (402.7 MB, dead after attention)
//   ws_h   f32  [N, 512] @ 0        (256 MB, reuses dead qkv region)
//   ws_ff  bf16 [N,1024] @ 256 MB   (256 MB, reuses dead qkv tail)
//   ctx    f32  [N, 512] = d_out    (d_out doubles as scratch; fully
//                                    overwritten by the final stages)
// =====================================================================
extern "C" void kernel_launch(void* const* d_in, const int* in_sizes, int n_in,
                              void* d_out, int out_size, void* d_ws, size_t ws_size,
                              hipStream_t stream) {
    const float* x    = (const float*)d_in[0];
    const float* wqkv = (const float*)d_in[1];
    const float* bqkv = (const float*)d_in[2];
    const float* wo   = (const float*)d_in[3];
    const float* bo   = (const float*)d_in[4];
    const float* w1   = (const float*)d_in[5];
    const float* b1   = (const float*)d_in[6];
    const float* w2   = (const float*)d_in[7];
    const float* b2   = (const float*)d_in[8];
    const float* g1   = (const float*)d_in[9];
    const float* be1  = (const float*)d_in[10];
    const float* g2   = (const float*)d_in[11];
    const float* be2  = (const float*)d_in[12];
    float* out = (float*)d_out;

    char* ws = (char*)d_ws;
    bf16*  ws_qkv = (bf16*)ws;
    float* ws_h   = (float*)ws;
    bf16*  ws_ff  = (bf16*)(ws + (size_t)NTOK * DMODEL * 4);
    float* ctx    = out;

    dim3 blk(256);

    // 1. qkv = x @ Wqkv^T + b           [N,1536] bf16
    gemm_nt<float, bf16, false, false>
        <<<dim3(1536 / 64, NTOK / 64), blk, 0, stream>>>(
            x, wqkv, bqkv, nullptr, ws_qkv, NTOK, 1536, 512);
    // 2. block attention -> ctx (d_out scratch) [N,512] f32
    attn_kernel<<<dim3(NB * NHEAD), blk, 0, stream>>>(ws_qkv, ctx);
    // 3. y = x + ctx @ Wo^T + bo -> ws_h
    gemm_nt<float, float, true, false>
        <<<dim3(512 / 64, NTOK / 64), blk, 0, stream>>>(
            ctx, wo, bo, x, ws_h, NTOK, 512, 512);
    // 4. h = LN1(y) in-place
    ln_rows<<<dim3(NTOK / 4), blk, 0, stream>>>(ws_h, ws_h, g1, be1);
    // 5. ff = gelu(h @ W1^T + b1) -> ws_ff bf16
    gemm_nt<float, bf16, false, true>
        <<<dim3(1024 / 64, NTOK / 64), blk, 0, stream>>>(
            ws_h, w1, b1, nullptr, ws_ff, NTOK, 1024, 512);
    // 6. y2 = h + ff @ W2^T + b2 -> d_out
    gemm_nt<bf16, float, true, false>
        <<<dim3(512 / 64, NTOK / 64), blk, 0, stream>>>(
            ws_ff, w2, b2, ws_h, out, NTOK, 512, 1024);
    // 7. out = LN2(y2) in-place on d_out
    ln_rows<<<dim3(NTOK / 4), blk, 0, stream>>>(out, out, g2, be2);
}